// Round 4
// baseline (283.019 us; speedup 1.0000x reference)
//
#include <hip/hip_runtime.h>
#include <math.h>

#define D2R      0.017453292519943295f
#define TWO_R    7917.6f                  /* 2 * 3958.8 miles */
#define RPI2     12435.698f               /* TWO_R * pi/2 */
#define TAU_LN2  0.17328679513998632f     /* tau * ln2 */
#define K_EXP2   5.770780163555854f       /* (1/tau) * log2(e) */
#define MBIG     1.0e30f
#define DMASK    2.0e30f

__device__ __forceinline__ float fexp2(float x) { return __builtin_amdgcn_exp2f(x); }

// ---------------- kernel 1: per-candidate trig precompute ----------------
// bin_coords flat (NBINS*M, 2) = [lon, lat] degrees.
// Store {cos(lat), sin(lat), cos(lon), sin(lon)}.
__global__ __launch_bounds__(256) void prep_cand(
    const float2* __restrict__ bc, float4* __restrict__ ct, int total) {
  int i = blockIdx.x * 256 + threadIdx.x;
  if (i < total) {
    float2 ll  = bc[i];
    float latr = ll.y * D2R;
    float lonr = ll.x * D2R;
    float sla, cla, slo, clo;
    __sincosf(latr, &sla, &cla);
    __sincosf(lonr, &slo, &clo);
    ct[i] = make_float4(cla, sla, clo, slo);
  }
}

// ---------------- kernel 2: fused haversine + online logsumexp ----------------
// One block (256 threads) per prediction, ITERS=16 candidates/thread.
// cos-expansion haversine: a = (1-cos dlat)/2 + c1*c2*(1-cos dlon)/2  (no v_sin).
// 6-deep explicit load ring (static names -> registers, loads pipelined).
// Two independent online-LSE accumulators (even/odd steps) halve the serial chain.
template <int ITERS>
__global__ __launch_bounds__(256) void lse_kernel(
    const float2* __restrict__ preds,
    const float4* __restrict__ ct,
    const int*    __restrict__ xv,
    const int*    __restrict__ bin_counts,
    float* __restrict__ accF, int* __restrict__ accI, int M) {
  const int b   = blockIdx.x;
  const int tid = threadIdx.x;

  const int bin = xv[3 * b] * 25 + xv[3 * b + 1] * 5 + xv[3 * b + 2];
  const int cnt = bin_counts[bin];

  const float2 p = preds[b];               // {lon, lat} degrees
  float cA, sA, cO, sO;                    // cos/sin of pred lat, lon
  __sincosf(p.y * D2R, &sA, &cA);
  __sincosf(p.x * D2R, &sO, &cO);

  const float4* __restrict__ cb = ct + (size_t)bin * (size_t)M;

  // ---- 6-deep prefetch ring ----
  float4 b0 = cb[tid + 0 * 256];
  float4 b1 = cb[tid + 1 * 256];
  float4 b2 = cb[tid + 2 * 256];
  float4 b3 = cb[tid + 3 * 256];
  float4 b4 = cb[tid + 4 * 256];
  float4 b5 = cb[tid + 5 * 256];

  float m0 = MBIG, s0a = 0.0f;
  float m1 = MBIG, s1a = 0.0f;

#define STEP(BUF, R)                                                        \
  {                                                                         \
    float4 cc = BUF;                                                        \
    if ((R) + 6 < ITERS) BUF = cb[tid + ((R) + 6) * 256];                   \
    float pp    = cA * cc.x;                      /* cos1*cos2        */    \
    float cdlat = fmaf(sA, cc.y, pp);             /* cos(dlat)        */    \
    float cdlon = fmaf(cO, cc.z, sO * cc.w);      /* cos(dlon)        */    \
    float t1 = fmaf(-0.5f, cdlat, 0.5f);                                    \
    float t2 = fmaf(-0.5f, cdlon, 0.5f);                                    \
    float a  = fminf(fmaxf(fmaf(pp, t2, t1), 0.0f), 1.0f);                  \
    float x  = sqrtf(a);                                                    \
    float pl = fmaf(x, -0.0012624911f, 0.0066700901f);                      \
    pl = fmaf(x, pl, -0.0170881256f);                                       \
    pl = fmaf(x, pl,  0.0308918810f);                                       \
    pl = fmaf(x, pl, -0.0501743046f);                                       \
    pl = fmaf(x, pl,  0.0889789874f);                                       \
    pl = fmaf(x, pl, -0.2145988016f);                                       \
    pl = fmaf(x, pl,  1.5707963050f);                                       \
    float w  = sqrtf(1.0f - x);                                             \
    float d  = fmaf(-TWO_R, w * pl, RPI2);        /* 2R*asin(sqrt(a)) */    \
    d = (tid + (R) * 256 < cnt) ? d : DMASK;                                \
    if ((R) & 1) {                                                          \
      float mn = fminf(m1, d);                                              \
      s1a = fmaf(s1a, fexp2((mn - m1) * K_EXP2),                            \
                 fexp2((mn - d) * K_EXP2));                                 \
      m1 = mn;                                                              \
    } else {                                                                \
      float mn = fminf(m0, d);                                              \
      s0a = fmaf(s0a, fexp2((mn - m0) * K_EXP2),                            \
                 fexp2((mn - d) * K_EXP2));                                 \
      m0 = mn;                                                              \
    }                                                                       \
  }

  STEP(b0, 0)  STEP(b1, 1)  STEP(b2, 2)  STEP(b3, 3)
  STEP(b4, 4)  STEP(b5, 5)  STEP(b0, 6)  STEP(b1, 7)
  STEP(b2, 8)  STEP(b3, 9)  STEP(b4, 10) STEP(b5, 11)
  STEP(b0, 12) STEP(b1, 13) STEP(b2, 14) STEP(b3, 15)
#undef STEP

  // ---- merge the two per-thread accumulators ----
  float m = fminf(m0, m1);
  float s = fmaf(s0a, fexp2((m - m0) * K_EXP2),
                 s1a * fexp2((m - m1) * K_EXP2));

  // ---- wave-level (m,s) merge ----
#pragma unroll
  for (int o = 32; o; o >>= 1) {
    float mo = __shfl_xor(m, o);
    float so = __shfl_xor(s, o);
    float mn = fminf(m, mo);
    s = fmaf(s, fexp2((mn - m) * K_EXP2), so * fexp2((mn - mo) * K_EXP2));
    m = mn;
  }

  // ---- cross-wave merge via LDS ----
  __shared__ float redm[4];
  __shared__ float reds[4];
  const int wave = tid >> 6;
  if ((tid & 63) == 0) { redm[wave] = m; reds[wave] = s; }
  __syncthreads();   // REQUIRED: tid 0 reads all four waves' partials below

  if (tid == 0 && cnt > 0) {
    float M4 = fminf(fminf(redm[0], redm[1]), fminf(redm[2], redm[3]));
    float S  = reds[0] * fexp2((M4 - redm[0]) * K_EXP2)
             + reds[1] * fexp2((M4 - redm[1]) * K_EXP2)
             + reds[2] * fexp2((M4 - redm[2]) * K_EXP2)
             + reds[3] * fexp2((M4 - redm[3]) * K_EXP2);
    float soft = M4 - TAU_LN2 * __log2f(S);   // = -tau * logsumexp(-d/tau)
    atomicAdd(accF, soft);
    atomicAdd(accI, 1);
  }
}

// ---------------- kernel 3: finalize ----------------
__global__ void fin_kernel(const float* __restrict__ accF,
                           const int* __restrict__ accI,
                           float* __restrict__ out) {
  int nv = *accI;
  if (nv < 1) nv = 1;
  out[0] = accF[0] / (float)nv;
}

extern "C" void kernel_launch(void* const* d_in, const int* in_sizes, int n_in,
                              void* d_out, int out_size, void* d_ws, size_t ws_size,
                              hipStream_t stream) {
  const float2* preds      = (const float2*)d_in[0];  // (B,2) [lon,lat]
  const float2* bin_coords = (const float2*)d_in[1];  // (125,M,2) [lon,lat]
  const int*    x_vals     = (const int*)d_in[2];     // (B,3)
  const int*    bin_counts = (const int*)d_in[3];     // (125,)
  float*        out        = (float*)d_out;

  const int B     = in_sizes[0] / 2;
  const int total = in_sizes[1] / 2;                  // NBINS * M
  const int NBINS = 125;
  const int M     = total / NBINS;                    // 4096

  float*  accF = (float*)d_ws;
  int*    accI = (int*)((char*)d_ws + 4);
  float4* ct   = (float4*)((char*)d_ws + 16);

  hipMemsetAsync(d_ws, 0, 16, stream);

  prep_cand<<<(total + 255) / 256, 256, 0, stream>>>(bin_coords, ct, total);

  lse_kernel<16><<<B, 256, 0, stream>>>(preds, ct, x_vals, bin_counts,
                                        accF, accI, M);

  fin_kernel<<<1, 1, 0, stream>>>(accF, accI, out);
}

// Round 5
// 134.828 us; speedup vs baseline: 2.0991x; 2.0991x over previous
//
#include <hip/hip_runtime.h>
#include <math.h>

#define D2R      0.017453292519943295f
#define TWO_R    7917.6f                  /* 2 * 3958.8 miles */
#define RPI2     12435.698f               /* TWO_R * pi/2 */
#define TAU_LN2  0.17328679513998632f     /* tau * ln2 */
#define K_EXP2   5.770780163555854f       /* (1/tau) * log2(e) */
#define MBIG     1.0e30f
#define DMASK    2.0e30f
#define NBINS    125
#define P        8                        /* preds per work item */

__device__ __forceinline__ float fexp2(float x) { return __builtin_amdgcn_exp2f(x); }
__device__ __forceinline__ float rfl(float x) {
  return __int_as_float(__builtin_amdgcn_readfirstlane(__float_as_int(x)));
}

// workspace layout (all rebuilt every launch; harness poisons ws to 0xAA)
struct Ws {
  float accF;          // softmin sum
  int   accI;          // n_valid
  int   nitems;        // number of work items
  int   pad;
  int   pbase[NBINS];  // pred-list base per bin
  int   pcnt[NBINS];   // preds per bin
  int   work[4096];    // (bin<<16)|group
};
#define PTRIG_OFF 17408  /* sizeof(Ws)=17400 rounded to 16 */

// ---------- kernel 1: group preds by bin, precompute pred trig ----------
// single block, 1024 threads
__global__ __launch_bounds__(1024) void group_kernel(
    const float2* __restrict__ preds, const int* __restrict__ xv,
    Ws* __restrict__ w, int B) {
  __shared__ int lcnt[NBINS], lbase[NBINS], lcur[NBINS], lg[NBINS];
  const int tid = threadIdx.x;

  for (int b = tid; b < NBINS; b += 1024) lcnt[b] = 0;
  __syncthreads();

  for (int i = tid; i < B; i += 1024) {
    int bin = xv[3 * i] * 25 + xv[3 * i + 1] * 5 + xv[3 * i + 2];
    atomicAdd(&lcnt[bin], 1);
  }
  __syncthreads();

  if (tid == 0) {
    int base = 0, gtot = 0;
    for (int b = 0; b < NBINS; ++b) {
      lbase[b] = base; base += lcnt[b];
      lg[b]    = gtot; gtot += (lcnt[b] + P - 1) / P;
    }
    w->nitems = gtot;
  }
  __syncthreads();

  for (int b = tid; b < NBINS; b += 1024) {
    lcur[b]     = lbase[b];
    w->pbase[b] = lbase[b];
    w->pcnt[b]  = lcnt[b];
    int g0 = lg[b], ng = (lcnt[b] + P - 1) / P;
    for (int g = 0; g < ng; ++g) w->work[g0 + g] = (b << 16) | g;
  }
  __syncthreads();

  float4* ptrig = (float4*)((char*)w + PTRIG_OFF);
  for (int i = tid; i < B; i += 1024) {
    int bin = xv[3 * i] * 25 + xv[3 * i + 1] * 5 + xv[3 * i + 2];
    int pos = atomicAdd(&lcur[bin], 1);
    float2 p = preds[i];
    float sA, cA, sO, cO;
    __sincosf(p.y * D2R, &sA, &cA);
    __sincosf(p.x * D2R, &sO, &cO);
    ptrig[pos] = make_float4(cA, sA, cO, sO);
  }
}

// ---------- kernel 2: bin-major fused haversine + online LSE ----------
// block = one (bin, group of P preds). 256 threads stream the bin's
// candidates (clipped at cnt); each candidate's trig is computed once and
// applied to all P preds (load amortized 8x -> compute-bound even with a
// 1-deep prefetch). Pred trig lives in SGPRs (readfirstlane).
__global__ __launch_bounds__(256) void lse_main(
    const float2* __restrict__ bc, const int* __restrict__ bin_counts,
    Ws* __restrict__ w, int M) {
  const int nitems = w->nitems;
  const int bid = blockIdx.x;
  if (bid >= nitems) return;
  const int tid = threadIdx.x;

  const int item   = w->work[bid];
  const int bin    = item >> 16;
  const int g      = item & 0xffff;
  const int npred  = w->pcnt[bin];
  const int pb     = w->pbase[bin] + g * P;
  const int pcount = min(P, npred - g * P);
  const int cnt    = bin_counts[bin];

  const float4* __restrict__ ptrig = (const float4*)((const char*)w + PTRIG_OFF);

  float cA[P], sA[P], cO[P], sO[P];
#pragma unroll
  for (int p = 0; p < P; ++p) {
    float4 t = ptrig[pb + min(p, pcount - 1)];
    cA[p] = rfl(t.x); sA[p] = rfl(t.y); cO[p] = rfl(t.z); sO[p] = rfl(t.w);
  }

  const float2* __restrict__ cb = bc + (size_t)bin * (size_t)M;
  const int cmax   = cnt - 1;
  const int nsteps = (cnt + 255) >> 8;

  float m[P], s[P];
#pragma unroll
  for (int p = 0; p < P; ++p) { m[p] = MBIG; s[p] = 0.0f; }

  float2 cur = cb[min(tid, cmax)];
  for (int step = 0; step < nsteps; ++step) {
    const int idx = (step << 8) + tid;
    float2 nxt = cb[min(idx + 256, cmax)];   // 1-deep prefetch (always in-bounds)
    float sla, cla, slo, clo;                // candidate trig, shared by P preds
    __sincosf(cur.y * D2R, &sla, &cla);
    __sincosf(cur.x * D2R, &slo, &clo);
    const bool valid = idx < cnt;
#pragma unroll
    for (int p = 0; p < P; ++p) {
      float pp    = cA[p] * cla;                    // cos1*cos2
      float cdlat = fmaf(sA[p], sla, pp);           // cos(dlat)
      float cdlon = fmaf(cO[p], clo, sO[p] * slo);  // cos(dlon)
      float t1 = fmaf(-0.5f, cdlat, 0.5f);
      float t2 = fmaf(-0.5f, cdlon, 0.5f);
      float a  = fminf(fmaxf(fmaf(pp, t2, t1), 0.0f), 1.0f);
      float x  = sqrtf(a);
      float pl = fmaf(x, -0.0012624911f, 0.0066700901f);  // A&S asin poly
      pl = fmaf(x, pl, -0.0170881256f);
      pl = fmaf(x, pl,  0.0308918810f);
      pl = fmaf(x, pl, -0.0501743046f);
      pl = fmaf(x, pl,  0.0889789874f);
      pl = fmaf(x, pl, -0.2145988016f);
      pl = fmaf(x, pl,  1.5707963050f);
      float wq = sqrtf(1.0f - x);
      float d  = fmaf(-TWO_R, wq * pl, RPI2);       // 2R*asin(sqrt(a))
      d = valid ? d : DMASK;
      float mn = fminf(m[p], d);
      s[p] = fmaf(s[p], fexp2((mn - m[p]) * K_EXP2), fexp2((mn - d) * K_EXP2));
      m[p] = mn;
    }
    cur = nxt;
  }

  // ---- wave-level (m,s) merge, per pred ----
#pragma unroll
  for (int p = 0; p < P; ++p) {
#pragma unroll
    for (int o = 32; o; o >>= 1) {
      float mo = __shfl_xor(m[p], o);
      float so = __shfl_xor(s[p], o);
      float mn = fminf(m[p], mo);
      s[p] = fmaf(s[p], fexp2((mn - m[p]) * K_EXP2),
                  so * fexp2((mn - mo) * K_EXP2));
      m[p] = mn;
    }
  }

  // ---- cross-wave merge ----
  __shared__ float redm[4][P], reds[4][P], lsoft[P];
  const int wave = tid >> 6;
  if ((tid & 63) == 0) {
#pragma unroll
    for (int p = 0; p < P; ++p) { redm[wave][p] = m[p]; reds[wave][p] = s[p]; }
  }
  __syncthreads();

  if (tid < P) {
    const int p = tid;
    float M4 = fminf(fminf(redm[0][p], redm[1][p]),
                     fminf(redm[2][p], redm[3][p]));
    float S  = reds[0][p] * fexp2((M4 - redm[0][p]) * K_EXP2)
             + reds[1][p] * fexp2((M4 - redm[1][p]) * K_EXP2)
             + reds[2][p] * fexp2((M4 - redm[2][p]) * K_EXP2)
             + reds[3][p] * fexp2((M4 - redm[3][p]) * K_EXP2);
    lsoft[p] = M4 - TAU_LN2 * __log2f(S);  // = -tau * logsumexp(-d/tau)
  }
  __syncthreads();

  if (tid == 0 && cnt > 0) {
    float acc = 0.0f;
    for (int p = 0; p < pcount; ++p) acc += lsoft[p];
    atomicAdd(&w->accF, acc);
    atomicAdd(&w->accI, pcount);
  }
}

// ---------- kernel 3: finalize ----------
__global__ void fin_kernel(const Ws* __restrict__ w, float* __restrict__ out) {
  int nv = w->accI;
  if (nv < 1) nv = 1;
  out[0] = w->accF / (float)nv;
}

extern "C" void kernel_launch(void* const* d_in, const int* in_sizes, int n_in,
                              void* d_out, int out_size, void* d_ws, size_t ws_size,
                              hipStream_t stream) {
  const float2* preds      = (const float2*)d_in[0];  // (B,2) [lon,lat] deg
  const float2* bin_coords = (const float2*)d_in[1];  // (125,M,2) [lon,lat] deg
  const int*    x_vals     = (const int*)d_in[2];     // (B,3)
  const int*    bin_counts = (const int*)d_in[3];     // (125,)
  float*        out        = (float*)d_out;

  const int B     = in_sizes[0] / 2;
  const int total = in_sizes[1] / 2;                  // NBINS * M
  const int M     = total / NBINS;                    // 4096

  Ws* w = (Ws*)d_ws;

  hipMemsetAsync(d_ws, 0, 16, stream);                // accF, accI

  group_kernel<<<1, 1024, 0, stream>>>(preds, x_vals, w, B);

  const int maxitems = (B + P - 1) / P + NBINS;       // >= nitems, size-only
  lse_main<<<maxitems, 256, 0, stream>>>(bin_coords, bin_counts, w, M);

  fin_kernel<<<1, 1, 0, stream>>>(w, out);
}